// Round 7
// baseline (368.036 us; speedup 1.0000x reference)
//
#include <hip/hip_runtime.h>
#include <math.h>

typedef unsigned long long u64;

#define NB 8192
#define NS 4096

// ws layout (bytes):
//   [0,16K)       pcnt[2048] u64      (K1 per-block nonzero count)
//   [16K,32K)     p3[2048]   double   (K3 per-block partial sums)
//   [32K,32K+4M)  maskbitsT[64][8192] u64   (bit-packed mask, word-transposed)
//   [+4M,+6M)     wbitsT[64][4096]    u64   (bit-packed W columns, word-transposed)
static const size_t OFF_CNT = 0;
static const size_t OFF_P3  = 16384;
static const size_t OFF_MB  = 32768;
static const size_t OFF_WB  = OFF_MB + (size_t)64 * 8192 * 8;

// Bit convention: word gw covers elements [gw*64, gw*64+64); bit p of the word
// corresponds to element offset 4*(p&15) + (p>>4). (Order-invariant under the
// AND+popcount contraction as long as K1 and K2 agree.)

// async global->LDS DMA, 16B per lane, wave-uniform LDS base + lane*16 dest,
// per-lane global source (m104/m173 pattern).
__device__ __forceinline__ void gload_lds16(const void* g, void* l) {
    __builtin_amdgcn_global_load_lds(
        (const __attribute__((address_space(1))) unsigned int*)g,
        (__attribute__((address_space(3))) unsigned int*)l, 16, 0, 0);
}

// ---------------- K1: pack mask bits (transposed) + count nonzeros ----------------
__global__ __launch_bounds__(256) void k1_pack_mask(
    const float* __restrict__ y, u64* __restrict__ mbT, u64* __restrict__ pcnt)
{
    __shared__ unsigned rc[4];
    const unsigned t = threadIdx.x;
    const unsigned lane = t & 63;
    const float4* y4 = (const float4*)y;
    u64 qi = (u64)blockIdx.x * 256 + t;       // float4 index
    const u64 stride = (u64)2048 * 256;       // 2^19
    unsigned lcnt = 0;
    #pragma unroll 4
    for (int it = 0; it < 16; ++it, qi += stride) {
        float4 v = y4[qi];
        u64 b0 = __ballot(v.x != 0.0f);
        u64 b1 = __ballot(v.y != 0.0f);
        u64 b2 = __ballot(v.z != 0.0f);
        u64 b3 = __ballot(v.w != 0.0f);
        lcnt += (v.x != 0.0f) + (v.y != 0.0f) + (v.z != 0.0f) + (v.w != 0.0f);
        if (lane < 4) {
            unsigned sh = lane << 4;
            u64 word = ((b0 >> sh) & 0xFFFFull)
                     | (((b1 >> sh) & 0xFFFFull) << 16)
                     | (((b2 >> sh) & 0xFFFFull) << 32)
                     | (((b3 >> sh) & 0xFFFFull) << 48);
            u64 gw = ((qi - lane) >> 4) + lane;        // word index, lane=g
            mbT[((gw & 63) << 13) + (gw >> 6)] = word;
        }
    }
    for (int off = 32; off; off >>= 1) lcnt += __shfl_down(lcnt, off, 64);
    if ((t & 63) == 0) rc[t >> 6] = lcnt;
    __syncthreads();
    if (t == 0) pcnt[blockIdx.x] = (u64)rc[0] + rc[1] + rc[2] + rc[3];
}

// ---------------- K2: pack W rows into bit columns (transposed, permuted bit order) ----------------
__global__ __launch_bounds__(256) void k2_pack_w(
    const float* __restrict__ W, u64* __restrict__ wbT)
{
    __shared__ float tile[64][65];
    const int j0 = blockIdx.x * 64;
    const int w  = blockIdx.y;            // W-row block: rows w*64..w*64+63
    const int i0 = w * 64;
    const int t = threadIdx.x;
    #pragma unroll
    for (int k = 0; k < 16; ++k) {
        int lin = t + (k << 8);
        int r = lin >> 6, c = lin & 63;
        tile[r][c] = W[(size_t)(i0 + r) * NS + (j0 + c)];
    }
    __syncthreads();
    const int lane = t & 63;
    const int wv = t >> 6;
    const int pr = ((lane & 15) << 2) + (lane >> 4);   // bit l <-> row offset 4*(l&15)+(l>>4)
    for (int jj = wv; jj < 64; jj += 4) {
        u64 bal = __ballot(tile[pr][jj] != 0.0f);
        if (lane == 0) wbT[((size_t)w << 12) + (j0 + jj)] = bal;
    }
}

// ---------------- K3: 128x128 tile popcount-GEMM ----------------
// Double-buffered 8-w stages staged by global_load_lds (no VGPR round-trip,
// no ds_writes). LDS dest is linear; the wT chunk-swizzle (involution
// c2 ^ ((c2>>4)&3), verified 0-conflict) is applied to the per-lane GLOBAL
// source address; read side unchanged.
__global__ __launch_bounds__(256) void k3_main(
    const float* __restrict__ y, const float* __restrict__ yhat,
    const u64* __restrict__ mbT, const u64* __restrict__ wbT,
    double* __restrict__ p3)
{
    __shared__ alignas(16) u64 mbuf[2][8 * 128];   // 8KB per buffer
    __shared__ alignas(16) u64 qbuf[2][8 * 128];   // 8KB per buffer (total 32KB)
    const int b0 = blockIdx.x << 7;            // 64 row-tiles
    const int j0 = blockIdx.y << 7;            // 32 col-tiles
    const int t  = threadIdx.x;
    const int lane = t & 63;
    const int v  = t >> 6;                     // wave id 0..3
    const int r0 = (t >> 4) << 3;              // 8 rows per thread
    const int cj = t & 15;                     // col-group; c0 = cj*8
    const unsigned sx = ((unsigned)cj >> 2) << 4;   // swizzle byte-XOR for q reads

    // per-lane staging sources: m linear, q chunk-swizzled at the source
    const u64* msrc = mbT + b0 + (size_t)(lane << 1);
    const u64* qsrc = wbT + j0 + (size_t)((lane ^ ((lane >> 4) & 3)) << 1);

    unsigned cnt[8][8];
    #pragma unroll
    for (int a = 0; a < 8; ++a)
        #pragma unroll
        for (int b = 0; b < 8; ++b) cnt[a][b] = 0;

    // stage s: 8 w-words (wl = s*8 + 0..7) -> buf. 16 chunks of 1KB; wave v
    // DMAs m-chunks {v, v+4} and q-chunks {v, v+4}. All bases wave-uniform.
    auto stage = [&](int s, int buf) {
        const int w0 = v, w1 = v + 4;
        const size_t wl0 = (size_t)((s << 3) + w0), wl1 = (size_t)((s << 3) + w1);
        gload_lds16(msrc + (wl0 << 13), &mbuf[buf][(size_t)w0 << 7]);
        gload_lds16(msrc + (wl1 << 13), &mbuf[buf][(size_t)w1 << 7]);
        gload_lds16(qsrc + (wl0 << 12), &qbuf[buf][(size_t)w0 << 7]);
        gload_lds16(qsrc + (wl1 << 12), &qbuf[buf][(size_t)w1 << 7]);
    };

    stage(0, 0);
    __syncthreads();   // drains vmcnt: buffer 0 ready

    #pragma unroll 1
    for (int s = 0; s < 8; ++s) {
        const int cb = s & 1;
        if (s < 7) stage(s + 1, cb ^ 1);   // async, hides under compute

        const char* mB = (const char*)mbuf[cb];
        const char* wB = (const char*)qbuf[cb];
        unsigned mo = (unsigned)(r0 << 3);
        unsigned qs = (unsigned)(cj << 6) + sx;
        #pragma unroll 2
        for (int w = 0; w < 8; ++w) {
            unsigned ml[16], ql[16];
            #pragma unroll
            for (int k = 0; k < 4; ++k) {
                uint4 a = *(const uint4*)(mB + mo + (k << 4));
                ml[4 * k + 0] = a.x; ml[4 * k + 1] = a.y;
                ml[4 * k + 2] = a.z; ml[4 * k + 3] = a.w;
                uint4 b = *(const uint4*)(wB + (qs ^ (unsigned)(k << 4)));
                ql[4 * k + 0] = b.x; ql[4 * k + 1] = b.y;
                ql[4 * k + 2] = b.z; ql[4 * k + 3] = b.w;
            }
            #pragma unroll
            for (int aa = 0; aa < 8; ++aa)
                #pragma unroll
                for (int bb = 0; bb < 8; ++bb) {
                    cnt[aa][bb] += __popc(ml[2 * aa] & ql[2 * bb]);
                    cnt[aa][bb] += __popc(ml[2 * aa + 1] & ql[2 * bb + 1]);
                }
            mo += 1024; qs += 1024;
        }
        __syncthreads();   // all reads done + next buffer's DMA drained
    }

    // epilogue: part = sum sq * (mask + 0.1*cnt) over this thread's 8x8 patch
    float part = 0.0f;
    const int c0 = cj << 3;
    #pragma unroll
    for (int aa = 0; aa < 8; ++aa) {
        size_t off = ((size_t)(b0 + r0 + aa) << 12) + (size_t)(j0 + c0);
        float ys[8], hs[8];
        *(float4*)&ys[0] = *(const float4*)(y + off);
        *(float4*)&ys[4] = *(const float4*)(y + off + 4);
        *(float4*)&hs[0] = *(const float4*)(yhat + off);
        *(float4*)&hs[4] = *(const float4*)(yhat + off + 4);
        #pragma unroll
        for (int bb = 0; bb < 8; ++bb) {
            float e = ys[bb] - hs[bb];
            float wgt = 0.1f * (float)cnt[aa][bb] + (ys[bb] != 0.0f ? 1.0f : 0.0f);
            part = fmaf(e * e, wgt, part);
        }
    }

    for (int off = 32; off; off >>= 1) part += __shfl_down(part, off, 64);
    float* red = (float*)mbuf;   // safe: barrier below before aliasing
    __syncthreads();
    if ((t & 63) == 0) red[t >> 6] = part;
    __syncthreads();
    if (t == 0)
        p3[(size_t)blockIdx.y * gridDim.x + blockIdx.x] =
            (double)red[0] + (double)red[1] + (double)red[2] + (double)red[3];
}

// ---------------- K4: final reduce + sqrt ----------------
__global__ __launch_bounds__(256) void k4_final(
    const u64* __restrict__ pcnt, const double* __restrict__ p3, float* __restrict__ out)
{
    __shared__ double rs[4];
    __shared__ u64 rcc[4];
    double s3 = 0.0;
    u64 c = 0;
    for (int i = threadIdx.x; i < 2048; i += 256) { s3 += p3[i]; c += pcnt[i]; }
    for (int off = 32; off; off >>= 1) {
        s3 += __shfl_down(s3, off, 64);
        c  += __shfl_down(c, off, 64);
    }
    int wv = threadIdx.x >> 6;
    if ((threadIdx.x & 63) == 0) { rs[wv] = s3; rcc[wv] = c; }
    __syncthreads();
    if (threadIdx.x == 0) {
        double S3 = rs[0] + rs[1] + rs[2] + rs[3];
        double C  = (double)(rcc[0] + rcc[1] + rcc[2] + rcc[3]);
        out[0] = (float)sqrt(S3 / C + 1e-6);
    }
}

extern "C" void kernel_launch(void* const* d_in, const int* in_sizes, int n_in,
                              void* d_out, int out_size, void* d_ws, size_t ws_size,
                              hipStream_t stream) {
    const float* yhat = (const float*)d_in[0];
    const float* y    = (const float*)d_in[1];
    const float* W    = (const float*)d_in[2];
    char* ws = (char*)d_ws;
    u64*    pcnt = (u64*)(ws + OFF_CNT);
    double* p3   = (double*)(ws + OFF_P3);
    u64*    mbT  = (u64*)(ws + OFF_MB);
    u64*    wbT  = (u64*)(ws + OFF_WB);

    k1_pack_mask<<<dim3(2048), dim3(256), 0, stream>>>(y, mbT, pcnt);
    k2_pack_w<<<dim3(64, 64), dim3(256), 0, stream>>>(W, wbT);
    k3_main<<<dim3(64, 32), dim3(256), 0, stream>>>(y, yhat, mbT, wbT, p3);
    k4_final<<<dim3(1), dim3(256), 0, stream>>>(pcnt, p3, (float*)d_out);
}

// Round 8
// 288.475 us; speedup vs baseline: 1.2758x; 1.2758x over previous
//
#include <hip/hip_runtime.h>
#include <math.h>

typedef unsigned long long u64;
typedef __attribute__((ext_vector_type(2))) unsigned long long u64x2;

#define NB 8192
#define NS 4096

// ws layout (bytes):
//   [0,16K)       pcnt[2048] u64      (K1 per-block nonzero count)
//   [16K,32K)     p3[2048]   double   (K3 per-block partial sums)
//   [32K,32K+4M)  maskbitsT[64][8192] u64   (bit-packed mask, word-transposed)
//   [+4M,+6M)     wbitsT[64][4096]    u64   (bit-packed W columns, word-transposed)
static const size_t OFF_CNT = 0;
static const size_t OFF_P3  = 16384;
static const size_t OFF_MB  = 32768;
static const size_t OFF_WB  = OFF_MB + (size_t)64 * 8192 * 8;

// Bit convention: word gw covers elements [gw*64, gw*64+64); bit p of the word
// corresponds to element offset 4*(p&15) + (p>>4). (Order-invariant under the
// AND+popcount contraction as long as K1 and K2 agree.)

// ---------------- K1: pack mask bits (transposed) + count nonzeros ----------------
__global__ __launch_bounds__(256) void k1_pack_mask(
    const float* __restrict__ y, u64* __restrict__ mbT, u64* __restrict__ pcnt)
{
    __shared__ unsigned rc[4];
    const unsigned t = threadIdx.x;
    const unsigned lane = t & 63;
    const float4* y4 = (const float4*)y;
    u64 qi = (u64)blockIdx.x * 256 + t;       // float4 index
    const u64 stride = (u64)2048 * 256;       // 2^19
    unsigned lcnt = 0;
    #pragma unroll 4
    for (int it = 0; it < 16; ++it, qi += stride) {
        float4 v = y4[qi];
        u64 b0 = __ballot(v.x != 0.0f);
        u64 b1 = __ballot(v.y != 0.0f);
        u64 b2 = __ballot(v.z != 0.0f);
        u64 b3 = __ballot(v.w != 0.0f);
        lcnt += (v.x != 0.0f) + (v.y != 0.0f) + (v.z != 0.0f) + (v.w != 0.0f);
        if (lane < 4) {
            unsigned sh = lane << 4;
            u64 word = ((b0 >> sh) & 0xFFFFull)
                     | (((b1 >> sh) & 0xFFFFull) << 16)
                     | (((b2 >> sh) & 0xFFFFull) << 32)
                     | (((b3 >> sh) & 0xFFFFull) << 48);
            u64 gw = ((qi - lane) >> 4) + lane;        // word index, lane=g
            mbT[((gw & 63) << 13) + (gw >> 6)] = word;
        }
    }
    for (int off = 32; off; off >>= 1) lcnt += __shfl_down(lcnt, off, 64);
    if ((t & 63) == 0) rc[t >> 6] = lcnt;
    __syncthreads();
    if (t == 0) pcnt[blockIdx.x] = (u64)rc[0] + rc[1] + rc[2] + rc[3];
}

// ---------------- K2: pack W rows into bit columns (transposed, permuted bit order) ----------------
__global__ __launch_bounds__(256) void k2_pack_w(
    const float* __restrict__ W, u64* __restrict__ wbT)
{
    __shared__ float tile[64][65];
    const int j0 = blockIdx.x * 64;
    const int w  = blockIdx.y;            // W-row block: rows w*64..w*64+63
    const int i0 = w * 64;
    const int t = threadIdx.x;
    #pragma unroll
    for (int k = 0; k < 16; ++k) {
        int lin = t + (k << 8);
        int r = lin >> 6, c = lin & 63;
        tile[r][c] = W[(size_t)(i0 + r) * NS + (j0 + c)];
    }
    __syncthreads();
    const int lane = t & 63;
    const int wv = t >> 6;
    const int pr = ((lane & 15) << 2) + (lane >> 4);   // bit l <-> row offset 4*(l&15)+(l>>4)
    for (int jj = wv; jj < 64; jj += 4) {
        u64 bal = __ballot(tile[pr][jj] != 0.0f);
        if (lane == 0) wbT[((size_t)w << 12) + (j0 + jj)] = bal;
    }
}

// ---------------- K3: 128x128 tile popcount-GEMM, 4x16-w stages, fused epilogue ----------------
// Inner loop: forced fused v_bcnt_u32_b32 (popcount-with-accumulate) via inline
// asm — guarantees 2 VALU per u32 pair (and + bcnt-acc). R5-R7 all plateaued at
// ~333-345us with 3 different staging schemes; suspect = unfused popc codegen.
__global__ __launch_bounds__(256) void k3_main(
    const float* __restrict__ y, const float* __restrict__ yhat,
    const u64* __restrict__ mbT, const u64* __restrict__ wbT,
    double* __restrict__ p3)
{
    __shared__ alignas(16) u64 mT[16 * 128];   // [w][r] linear, 16KB
    __shared__ alignas(16) u64 wT[16 * 128];   // [w][c] XOR-swizzled chunks, 16KB
    const int b0 = blockIdx.x << 7;            // 64 row-tiles
    const int j0 = blockIdx.y << 7;            // 32 col-tiles
    const int t  = threadIdx.x;
    const int r0 = (t >> 4) << 3;              // 8 rows per thread
    const int cj = t & 15;                     // col-group; c0 = cj*8
    const unsigned sx = ((unsigned)cj >> 2) << 4;   // swizzle byte-XOR for q reads

    unsigned cnt[8][8];
    #pragma unroll
    for (int a = 0; a < 8; ++a)
        #pragma unroll
        for (int b = 0; b < 8; ++b) cnt[a][b] = 0;

    char* mB = (char*)mT;
    char* wB = (char*)wT;

    #pragma unroll 1
    for (int s = 0; s < 4; ++s) {
        // load this stage's 16 w-rows into regs (short-lived, consumed immediately)
        u64x2 gm[4], gq[4];
        #pragma unroll
        for (int k = 0; k < 4; ++k) {
            int lin = t + (k << 8);
            int wl = (s << 4) + (lin >> 6), c2 = lin & 63;
            gm[k] = *(const u64x2*)&mbT[((size_t)wl << 13) + b0 + 2 * c2];
            gq[k] = *(const u64x2*)&wbT[((size_t)wl << 12) + j0 + 2 * c2];
        }
        __syncthreads();   // previous stage's compute done before overwrite
        #pragma unroll
        for (int k = 0; k < 4; ++k) {
            int lin = t + (k << 8);
            int wl = lin >> 6, c2 = lin & 63;
            int p = c2 ^ ((c2 >> 4) & 3);
            *(u64x2*)(mB + (wl << 10) + (c2 << 4)) = gm[k];
            *(u64x2*)(wB + (wl << 10) + (p << 4)) = gq[k];
        }
        __syncthreads();

        unsigned mo = (unsigned)(r0 << 3);
        unsigned qs = (unsigned)(cj << 6) + sx;
        #pragma unroll 2
        for (int w = 0; w < 16; ++w) {
            unsigned ml[16], ql[16];
            #pragma unroll
            for (int k = 0; k < 4; ++k) {
                uint4 a = *(const uint4*)(mB + mo + (k << 4));
                ml[4 * k + 0] = a.x; ml[4 * k + 1] = a.y;
                ml[4 * k + 2] = a.z; ml[4 * k + 3] = a.w;
                uint4 b = *(const uint4*)(wB + (qs ^ (unsigned)(k << 4)));
                ql[4 * k + 0] = b.x; ql[4 * k + 1] = b.y;
                ql[4 * k + 2] = b.z; ql[4 * k + 3] = b.w;
            }
            #pragma unroll
            for (int aa = 0; aa < 8; ++aa)
                #pragma unroll
                for (int bb = 0; bb < 8; ++bb) {
                    unsigned x0 = ml[2 * aa] & ql[2 * bb];
                    unsigned x1 = ml[2 * aa + 1] & ql[2 * bb + 1];
                    asm("v_bcnt_u32_b32 %0, %1, %0" : "+v"(cnt[aa][bb]) : "v"(x0));
                    asm("v_bcnt_u32_b32 %0, %1, %0" : "+v"(cnt[aa][bb]) : "v"(x1));
                }
            mo += 1024; qs += 1024;
        }
    }

    // epilogue: part = sum sq * (mask + 0.1*cnt) over this thread's 8x8 patch
    float part = 0.0f;
    const int c0 = cj << 3;
    #pragma unroll
    for (int aa = 0; aa < 8; ++aa) {
        size_t off = ((size_t)(b0 + r0 + aa) << 12) + (size_t)(j0 + c0);
        float ys[8], hs[8];
        *(float4*)&ys[0] = *(const float4*)(y + off);
        *(float4*)&ys[4] = *(const float4*)(y + off + 4);
        *(float4*)&hs[0] = *(const float4*)(yhat + off);
        *(float4*)&hs[4] = *(const float4*)(yhat + off + 4);
        #pragma unroll
        for (int bb = 0; bb < 8; ++bb) {
            float e = ys[bb] - hs[bb];
            float wgt = 0.1f * (float)cnt[aa][bb] + (ys[bb] != 0.0f ? 1.0f : 0.0f);
            part = fmaf(e * e, wgt, part);
        }
    }

    for (int off = 32; off; off >>= 1) part += __shfl_down(part, off, 64);
    float* red = (float*)mT;    // safe: barrier below before aliasing
    __syncthreads();
    if ((t & 63) == 0) red[t >> 6] = part;
    __syncthreads();
    if (t == 0)
        p3[(size_t)blockIdx.y * gridDim.x + blockIdx.x] =
            (double)red[0] + (double)red[1] + (double)red[2] + (double)red[3];
}

// ---------------- K4: final reduce + sqrt ----------------
__global__ __launch_bounds__(256) void k4_final(
    const u64* __restrict__ pcnt, const double* __restrict__ p3, float* __restrict__ out)
{
    __shared__ double rs[4];
    __shared__ u64 rcc[4];
    double s3 = 0.0;
    u64 c = 0;
    for (int i = threadIdx.x; i < 2048; i += 256) { s3 += p3[i]; c += pcnt[i]; }
    for (int off = 32; off; off >>= 1) {
        s3 += __shfl_down(s3, off, 64);
        c  += __shfl_down(c, off, 64);
    }
    int wv = threadIdx.x >> 6;
    if ((threadIdx.x & 63) == 0) { rs[wv] = s3; rcc[wv] = c; }
    __syncthreads();
    if (threadIdx.x == 0) {
        double S3 = rs[0] + rs[1] + rs[2] + rs[3];
        double C  = (double)(rcc[0] + rcc[1] + rcc[2] + rcc[3]);
        out[0] = (float)sqrt(S3 / C + 1e-6);
    }
}

extern "C" void kernel_launch(void* const* d_in, const int* in_sizes, int n_in,
                              void* d_out, int out_size, void* d_ws, size_t ws_size,
                              hipStream_t stream) {
    const float* yhat = (const float*)d_in[0];
    const float* y    = (const float*)d_in[1];
    const float* W    = (const float*)d_in[2];
    char* ws = (char*)d_ws;
    u64*    pcnt = (u64*)(ws + OFF_CNT);
    double* p3   = (double*)(ws + OFF_P3);
    u64*    mbT  = (u64*)(ws + OFF_MB);
    u64*    wbT  = (u64*)(ws + OFF_WB);

    k1_pack_mask<<<dim3(2048), dim3(256), 0, stream>>>(y, mbT, pcnt);
    k2_pack_w<<<dim3(64, 64), dim3(256), 0, stream>>>(W, wbT);
    k3_main<<<dim3(64, 32), dim3(256), 0, stream>>>(y, yhat, mbT, wbT, p3);
    k4_final<<<dim3(1), dim3(256), 0, stream>>>(pcnt, p3, (float*)d_out);
}

// Round 9
// 249.807 us; speedup vs baseline: 1.4733x; 1.1548x over previous
//
#include <hip/hip_runtime.h>
#include <math.h>

typedef unsigned long long u64;
typedef unsigned int u32;
typedef unsigned char u8;
typedef __attribute__((ext_vector_type(2))) unsigned long long u64x2;
typedef __attribute__((ext_vector_type(4))) int i32x4;

#define NB 8192
#define NS 4096

// ---- old (popcount) path ws layout ----
static const size_t OFF_CNT = 0;
static const size_t OFF_P3  = 16384;
static const size_t OFF_MB  = 32768;
static const size_t OFF_WB  = OFF_MB + (size_t)64 * 8192 * 8;
// ---- new (i8 MFMA) path ws layout ----
static const size_t OFF_M8  = 32768;                       // mask8 [8192][4096] i8
static const size_t OFF_BT  = OFF_M8 + (size_t)NB * NS;    // Bt    [4096][4096] i8 (Bt[j][i]=Wbin[i][j])
static const size_t WS_NEED = OFF_BT + (size_t)NS * NS;

__device__ __forceinline__ void gload_lds16(const void* g, void* l) {
    __builtin_amdgcn_global_load_lds(
        (const __attribute__((address_space(1))) unsigned int*)g,
        (__attribute__((address_space(3))) unsigned int*)l, 16, 0, 0);
}

// ================= i8-MFMA path =================

// K1b: mask8[b][i] = (y!=0), linear i8; + per-block nonzero count
__global__ __launch_bounds__(256) void k1b_mask8(
    const float* __restrict__ y, u32* __restrict__ m8, u64* __restrict__ pcnt)
{
    __shared__ unsigned rc[4];
    const int t = threadIdx.x;
    const float4* y4 = (const float4*)y;
    size_t base = (size_t)blockIdx.x * 4096 + t;   // float4 index; 16 per thread
    unsigned lcnt = 0;
    #pragma unroll 4
    for (int k = 0; k < 16; ++k) {
        float4 v = y4[base + (size_t)k * 256];
        unsigned b0 = v.x != 0.0f, b1 = v.y != 0.0f, b2 = v.z != 0.0f, b3 = v.w != 0.0f;
        lcnt += b0 + b1 + b2 + b3;
        m8[base + (size_t)k * 256] = b0 | (b1 << 8) | (b2 << 16) | (b3 << 24);
    }
    for (int off = 32; off; off >>= 1) lcnt += __shfl_down(lcnt, off, 64);
    if ((t & 63) == 0) rc[t >> 6] = lcnt;
    __syncthreads();
    if (t == 0) pcnt[blockIdx.x] = (u64)rc[0] + rc[1] + rc[2] + rc[3];
}

// K2b: Bt[j][i] = (W[i][j] != 0) as i8  (64x64 f32 LDS transpose tiles)
__global__ __launch_bounds__(256) void k2b_bt(
    const float* __restrict__ W, u32* __restrict__ bt)
{
    __shared__ float tile[64][65];
    const int j0 = blockIdx.x * 64, i0 = blockIdx.y * 64;
    const int t = threadIdx.x;
    #pragma unroll
    for (int k = 0; k < 16; ++k) {
        int lin = t + (k << 8);
        int r = lin >> 6, c = lin & 63;
        tile[r][c] = W[(size_t)(i0 + r) * NS + (j0 + c)];
    }
    __syncthreads();
    const int jj = t >> 2, ck = t & 3;
    u32 wd[4];
    #pragma unroll
    for (int g = 0; g < 4; ++g) {
        u32 u = 0;
        #pragma unroll
        for (int bb = 0; bb < 4; ++bb)
            u |= (tile[ck * 16 + g * 4 + bb][jj] != 0.0f ? 1u : 0u) << (8 * bb);
        wd[g] = u;
    }
    uint4 out = make_uint4(wd[0], wd[1], wd[2], wd[3]);
    *(uint4*)&bt[(((size_t)(j0 + jj) << 12) + (size_t)(i0 + ck * 16)) >> 2] = out;
}

// K3b: 128x128-tile i8 GEMM cnt = mask8 @ Wbin^T on the MFMA pipe (m97 recipe),
// fused sq-weighted epilogue. LDS: A [128][64B] + B [128][64B] = 16KB, linear;
// staging via global_load_lds (linear dest), read-side chunk swizzle
// (l>>4)^(row&3) with matching inverse on the DMA *source* (rule #21).
__global__ __launch_bounds__(256) void k3b_mfma(
    const float* __restrict__ y, const float* __restrict__ yhat,
    const u8* __restrict__ m8, const u8* __restrict__ bt,
    double* __restrict__ p3)
{
    __shared__ alignas(16) u8 lds[16384];
    const int b0 = blockIdx.x << 7;    // 64 row tiles
    const int j0 = blockIdx.y << 7;    // 32 col tiles
    const int t = threadIdx.x, l = t & 63, wv = t >> 6;
    const int wr = wv >> 1, wc = wv & 1;

    // DMA: slot s=t covers (row=t>>2, pos=t&3); fetch logical chunk pos^row
    const int row4 = t >> 2, pos = t & 3;
    const int chunk = pos ^ (row4 & 3);
    const u8* srcA = m8 + ((size_t)(b0 + row4) << 12) + ((size_t)chunk << 4);
    const u8* srcB = bt + ((size_t)(j0 + row4) << 12) + ((size_t)chunk << 4);
    u8* dA = &lds[(size_t)wv << 10];          // wave-uniform bases
    u8* dB = &lds[8192 + ((size_t)wv << 10)];

    // fragment read bases (row = (l&15) within 16-row frag; chunk XOR row&3)
    const int frbase = ((wr << 6) + (l & 15)) * 64 + (((l >> 4) ^ (l & 3)) << 4);
    const int fcbase = 8192 + ((wc << 6) + (l & 15)) * 64 + (((l >> 4) ^ (l & 3)) << 4);

    i32x4 acc[4][4];
    #pragma unroll
    for (int i = 0; i < 4; ++i)
        #pragma unroll
        for (int j = 0; j < 4; ++j) acc[i][j] = (i32x4){0, 0, 0, 0};

    #pragma unroll 1
    for (int ks = 0; ks < 64; ++ks) {
        gload_lds16(srcA, dA);
        gload_lds16(srcA + ((size_t)64 << 12), dA + 4096);
        gload_lds16(srcB, dB);
        gload_lds16(srcB + ((size_t)64 << 12), dB + 4096);
        srcA += 64; srcB += 64;
        __syncthreads();   // drains vmcnt: tile ready
        i32x4 a[4], b[4];
        #pragma unroll
        for (int f = 0; f < 4; ++f) {
            a[f] = *(const i32x4*)&lds[frbase + f * 1024];
            b[f] = *(const i32x4*)&lds[fcbase + f * 1024];
        }
        #pragma unroll
        for (int fr = 0; fr < 4; ++fr)
            #pragma unroll
            for (int fc = 0; fc < 4; ++fc)
                acc[fr][fc] = __builtin_amdgcn_mfma_i32_16x16x64_i8(
                    a[fr], b[fc], acc[fr][fc], 0, 0, 0);
        __syncthreads();   // reads done before next stage overwrites
    }

    // epilogue: C/D map col=l&15, row=(l>>4)*4+q (m89/m121, dtype-independent)
    float part = 0.0f;
    const int col = j0 + (wc << 6) + (l & 15);
    #pragma unroll
    for (int fr = 0; fr < 4; ++fr)
        #pragma unroll
        for (int q = 0; q < 4; ++q) {
            size_t rbase = ((size_t)(b0 + (wr << 6) + (fr << 4) + ((l >> 4) << 2) + q) << 12) + col;
            #pragma unroll
            for (int fc = 0; fc < 4; ++fc) {
                float yv = y[rbase + (fc << 4)];
                float hv = yhat[rbase + (fc << 4)];
                float e = yv - hv;
                float wgt = 0.1f * (float)acc[fr][fc][q] + (yv != 0.0f ? 1.0f : 0.0f);
                part = fmaf(e * e, wgt, part);
            }
        }

    for (int off = 32; off; off >>= 1) part += __shfl_down(part, off, 64);
    float* red = (float*)lds;
    __syncthreads();
    if ((t & 63) == 0) red[t >> 6] = part;
    __syncthreads();
    if (t == 0)
        p3[(size_t)blockIdx.y * gridDim.x + blockIdx.x] =
            (double)red[0] + (double)red[1] + (double)red[2] + (double)red[3];
}

// ================= popcount fallback path (R8, passing @288us) =================

__global__ __launch_bounds__(256) void k1_pack_mask(
    const float* __restrict__ y, u64* __restrict__ mbT, u64* __restrict__ pcnt)
{
    __shared__ unsigned rc[4];
    const unsigned t = threadIdx.x;
    const unsigned lane = t & 63;
    const float4* y4 = (const float4*)y;
    u64 qi = (u64)blockIdx.x * 256 + t;
    const u64 stride = (u64)2048 * 256;
    unsigned lcnt = 0;
    #pragma unroll 4
    for (int it = 0; it < 16; ++it, qi += stride) {
        float4 v = y4[qi];
        u64 b0 = __ballot(v.x != 0.0f);
        u64 b1 = __ballot(v.y != 0.0f);
        u64 b2 = __ballot(v.z != 0.0f);
        u64 b3 = __ballot(v.w != 0.0f);
        lcnt += (v.x != 0.0f) + (v.y != 0.0f) + (v.z != 0.0f) + (v.w != 0.0f);
        if (lane < 4) {
            unsigned sh = lane << 4;
            u64 word = ((b0 >> sh) & 0xFFFFull)
                     | (((b1 >> sh) & 0xFFFFull) << 16)
                     | (((b2 >> sh) & 0xFFFFull) << 32)
                     | (((b3 >> sh) & 0xFFFFull) << 48);
            u64 gw = ((qi - lane) >> 4) + lane;
            mbT[((gw & 63) << 13) + (gw >> 6)] = word;
        }
    }
    for (int off = 32; off; off >>= 1) lcnt += __shfl_down(lcnt, off, 64);
    if ((t & 63) == 0) rc[t >> 6] = lcnt;
    __syncthreads();
    if (t == 0) pcnt[blockIdx.x] = (u64)rc[0] + rc[1] + rc[2] + rc[3];
}

__global__ __launch_bounds__(256) void k2_pack_w(
    const float* __restrict__ W, u64* __restrict__ wbT)
{
    __shared__ float tile[64][65];
    const int j0 = blockIdx.x * 64;
    const int w  = blockIdx.y;
    const int i0 = w * 64;
    const int t = threadIdx.x;
    #pragma unroll
    for (int k = 0; k < 16; ++k) {
        int lin = t + (k << 8);
        int r = lin >> 6, c = lin & 63;
        tile[r][c] = W[(size_t)(i0 + r) * NS + (j0 + c)];
    }
    __syncthreads();
    const int lane = t & 63;
    const int wvv = t >> 6;
    const int pr = ((lane & 15) << 2) + (lane >> 4);
    for (int jj = wvv; jj < 64; jj += 4) {
        u64 bal = __ballot(tile[pr][jj] != 0.0f);
        if (lane == 0) wbT[((size_t)w << 12) + (j0 + jj)] = bal;
    }
}

__global__ __launch_bounds__(256) void k3_main(
    const float* __restrict__ y, const float* __restrict__ yhat,
    const u64* __restrict__ mbT, const u64* __restrict__ wbT,
    double* __restrict__ p3)
{
    __shared__ alignas(16) u64 mT[16 * 128];
    __shared__ alignas(16) u64 wT[16 * 128];
    const int b0 = blockIdx.x << 7;
    const int j0 = blockIdx.y << 7;
    const int t  = threadIdx.x;
    const int r0 = (t >> 4) << 3;
    const int cj = t & 15;
    const unsigned sx = ((unsigned)cj >> 2) << 4;

    unsigned cnt[8][8];
    #pragma unroll
    for (int a = 0; a < 8; ++a)
        #pragma unroll
        for (int b = 0; b < 8; ++b) cnt[a][b] = 0;

    char* mB = (char*)mT;
    char* wB = (char*)wT;

    #pragma unroll 1
    for (int s = 0; s < 4; ++s) {
        u64x2 gm[4], gq[4];
        #pragma unroll
        for (int k = 0; k < 4; ++k) {
            int lin = t + (k << 8);
            int wl = (s << 4) + (lin >> 6), c2 = lin & 63;
            gm[k] = *(const u64x2*)&mbT[((size_t)wl << 13) + b0 + 2 * c2];
            gq[k] = *(const u64x2*)&wbT[((size_t)wl << 12) + j0 + 2 * c2];
        }
        __syncthreads();
        #pragma unroll
        for (int k = 0; k < 4; ++k) {
            int lin = t + (k << 8);
            int wl = lin >> 6, c2 = lin & 63;
            int p = c2 ^ ((c2 >> 4) & 3);
            *(u64x2*)(mB + (wl << 10) + (c2 << 4)) = gm[k];
            *(u64x2*)(wB + (wl << 10) + (p << 4)) = gq[k];
        }
        __syncthreads();

        unsigned mo = (unsigned)(r0 << 3);
        unsigned qs = (unsigned)(cj << 6) + sx;
        #pragma unroll 2
        for (int w = 0; w < 16; ++w) {
            unsigned ml[16], ql[16];
            #pragma unroll
            for (int k = 0; k < 4; ++k) {
                uint4 a = *(const uint4*)(mB + mo + (k << 4));
                ml[4 * k + 0] = a.x; ml[4 * k + 1] = a.y;
                ml[4 * k + 2] = a.z; ml[4 * k + 3] = a.w;
                uint4 b = *(const uint4*)(wB + (qs ^ (unsigned)(k << 4)));
                ql[4 * k + 0] = b.x; ql[4 * k + 1] = b.y;
                ql[4 * k + 2] = b.z; ql[4 * k + 3] = b.w;
            }
            #pragma unroll
            for (int aa = 0; aa < 8; ++aa)
                #pragma unroll
                for (int bb = 0; bb < 8; ++bb) {
                    unsigned x0 = ml[2 * aa] & ql[2 * bb];
                    unsigned x1 = ml[2 * aa + 1] & ql[2 * bb + 1];
                    asm("v_bcnt_u32_b32 %0, %1, %0" : "+v"(cnt[aa][bb]) : "v"(x0));
                    asm("v_bcnt_u32_b32 %0, %1, %0" : "+v"(cnt[aa][bb]) : "v"(x1));
                }
            mo += 1024; qs += 1024;
        }
    }

    float part = 0.0f;
    const int c0 = cj << 3;
    #pragma unroll
    for (int aa = 0; aa < 8; ++aa) {
        size_t off = ((size_t)(b0 + r0 + aa) << 12) + (size_t)(j0 + c0);
        float ys[8], hs[8];
        *(float4*)&ys[0] = *(const float4*)(y + off);
        *(float4*)&ys[4] = *(const float4*)(y + off + 4);
        *(float4*)&hs[0] = *(const float4*)(yhat + off);
        *(float4*)&hs[4] = *(const float4*)(yhat + off + 4);
        #pragma unroll
        for (int bb = 0; bb < 8; ++bb) {
            float e = ys[bb] - hs[bb];
            float wgt = 0.1f * (float)cnt[aa][bb] + (ys[bb] != 0.0f ? 1.0f : 0.0f);
            part = fmaf(e * e, wgt, part);
        }
    }

    for (int off = 32; off; off >>= 1) part += __shfl_down(part, off, 64);
    float* red = (float*)mT;
    __syncthreads();
    if ((t & 63) == 0) red[t >> 6] = part;
    __syncthreads();
    if (t == 0)
        p3[(size_t)blockIdx.y * gridDim.x + blockIdx.x] =
            (double)red[0] + (double)red[1] + (double)red[2] + (double)red[3];
}

// ---------------- K4: final reduce + sqrt (shared) ----------------
__global__ __launch_bounds__(256) void k4_final(
    const u64* __restrict__ pcnt, const double* __restrict__ p3, float* __restrict__ out)
{
    __shared__ double rs[4];
    __shared__ u64 rcc[4];
    double s3 = 0.0;
    u64 c = 0;
    for (int i = threadIdx.x; i < 2048; i += 256) { s3 += p3[i]; c += pcnt[i]; }
    for (int off = 32; off; off >>= 1) {
        s3 += __shfl_down(s3, off, 64);
        c  += __shfl_down(c, off, 64);
    }
    int wv = threadIdx.x >> 6;
    if ((threadIdx.x & 63) == 0) { rs[wv] = s3; rcc[wv] = c; }
    __syncthreads();
    if (threadIdx.x == 0) {
        double S3 = rs[0] + rs[1] + rs[2] + rs[3];
        double C  = (double)(rcc[0] + rcc[1] + rcc[2] + rcc[3]);
        out[0] = (float)sqrt(S3 / C + 1e-6);
    }
}

extern "C" void kernel_launch(void* const* d_in, const int* in_sizes, int n_in,
                              void* d_out, int out_size, void* d_ws, size_t ws_size,
                              hipStream_t stream) {
    const float* yhat = (const float*)d_in[0];
    const float* y    = (const float*)d_in[1];
    const float* W    = (const float*)d_in[2];
    char* ws = (char*)d_ws;
    u64*    pcnt = (u64*)(ws + OFF_CNT);
    double* p3   = (double*)(ws + OFF_P3);

    if (ws_size >= WS_NEED) {
        u32* m8 = (u32*)(ws + OFF_M8);
        u32* bt = (u32*)(ws + OFF_BT);
        k1b_mask8<<<dim3(2048), dim3(256), 0, stream>>>(y, m8, pcnt);
        k2b_bt<<<dim3(64, 64), dim3(256), 0, stream>>>(W, bt);
        k3b_mfma<<<dim3(64, 32), dim3(256), 0, stream>>>(
            y, yhat, (const u8*)m8, (const u8*)bt, p3);
        k4_final<<<dim3(1), dim3(256), 0, stream>>>(pcnt, p3, (float*)d_out);
    } else {
        u64* mbT = (u64*)(ws + OFF_MB);
        u64* wbT = (u64*)(ws + OFF_WB);
        k1_pack_mask<<<dim3(2048), dim3(256), 0, stream>>>(y, mbT, pcnt);
        k2_pack_w<<<dim3(64, 64), dim3(256), 0, stream>>>(W, wbT);
        k3_main<<<dim3(64, 32), dim3(256), 0, stream>>>(y, yhat, mbT, wbT, p3);
        k4_final<<<dim3(1), dim3(256), 0, stream>>>(pcnt, p3, (float*)d_out);
    }
}

// Round 10
// 226.166 us; speedup vs baseline: 1.6273x; 1.1045x over previous
//
#include <hip/hip_runtime.h>
#include <math.h>

typedef unsigned long long u64;
typedef unsigned int u32;
typedef unsigned char u8;
typedef __attribute__((ext_vector_type(2))) unsigned long long u64x2;
typedef __attribute__((ext_vector_type(4))) int i32x4;

#define NB 8192
#define NS 4096

// ---- old (popcount) path ws layout ----
static const size_t OFF_CNT = 0;
static const size_t OFF_P3  = 16384;
static const size_t OFF_MB  = 32768;
static const size_t OFF_WB  = OFF_MB + (size_t)64 * 8192 * 8;
// ---- new (i8 MFMA) path ws layout ----
static const size_t OFF_M8  = 32768;                       // mask8 [8192][4096] i8
static const size_t OFF_BT  = OFF_M8 + (size_t)NB * NS;    // Bt    [4096][4096] i8 (Bt[j][i]=Wbin[i][j])
static const size_t WS_NEED = OFF_BT + (size_t)NS * NS;

__device__ __forceinline__ void gload_lds16(const void* g, void* l) {
    __builtin_amdgcn_global_load_lds(
        (const __attribute__((address_space(1))) unsigned int*)g,
        (__attribute__((address_space(3))) unsigned int*)l, 16, 0, 0);
}

// ================= i8-MFMA path =================

// K1b: mask8[b][i] = (y!=0), linear i8; + per-block nonzero count
__global__ __launch_bounds__(256) void k1b_mask8(
    const float* __restrict__ y, u32* __restrict__ m8, u64* __restrict__ pcnt)
{
    __shared__ unsigned rc[4];
    const int t = threadIdx.x;
    const float4* y4 = (const float4*)y;
    size_t base = (size_t)blockIdx.x * 4096 + t;   // float4 index; 16 per thread
    unsigned lcnt = 0;
    #pragma unroll 4
    for (int k = 0; k < 16; ++k) {
        float4 v = y4[base + (size_t)k * 256];
        unsigned b0 = v.x != 0.0f, b1 = v.y != 0.0f, b2 = v.z != 0.0f, b3 = v.w != 0.0f;
        lcnt += b0 + b1 + b2 + b3;
        m8[base + (size_t)k * 256] = b0 | (b1 << 8) | (b2 << 16) | (b3 << 24);
    }
    for (int off = 32; off; off >>= 1) lcnt += __shfl_down(lcnt, off, 64);
    if ((t & 63) == 0) rc[t >> 6] = lcnt;
    __syncthreads();
    if (t == 0) pcnt[blockIdx.x] = (u64)rc[0] + rc[1] + rc[2] + rc[3];
}

// K2b: Bt[j][i] = (W[i][j] != 0) as i8  (64x64 f32 LDS transpose tiles)
__global__ __launch_bounds__(256) void k2b_bt(
    const float* __restrict__ W, u32* __restrict__ bt)
{
    __shared__ float tile[64][65];
    const int j0 = blockIdx.x * 64, i0 = blockIdx.y * 64;
    const int t = threadIdx.x;
    #pragma unroll
    for (int k = 0; k < 16; ++k) {
        int lin = t + (k << 8);
        int r = lin >> 6, c = lin & 63;
        tile[r][c] = W[(size_t)(i0 + r) * NS + (j0 + c)];
    }
    __syncthreads();
    const int jj = t >> 2, ck = t & 3;
    u32 wd[4];
    #pragma unroll
    for (int g = 0; g < 4; ++g) {
        u32 u = 0;
        #pragma unroll
        for (int bb = 0; bb < 4; ++bb)
            u |= (tile[ck * 16 + g * 4 + bb][jj] != 0.0f ? 1u : 0u) << (8 * bb);
        wd[g] = u;
    }
    uint4 out = make_uint4(wd[0], wd[1], wd[2], wd[3]);
    *(uint4*)&bt[(((size_t)(j0 + jj) << 12) + (size_t)(i0 + ck * 16)) >> 2] = out;
}

// K3b: 128x128-tile i8 GEMM cnt = mask8 @ Wbin^T on the MFMA pipe.
// v2: (a) swizzle f(r) = (r>>1)&3 -> pure 2-way (free) bank pattern on
//     ds_read_b128 (R9's f=r&3 was 4-way: 16r mod 32 ignores r&3);
// (b) double-buffered LDS, stage(s+1) issued before compute(s), one
//     barrier per K-iter -> DMA latency hides under MFMA+ds_read.
__global__ __launch_bounds__(256) void k3b_mfma(
    const float* __restrict__ y, const float* __restrict__ yhat,
    const u8* __restrict__ m8, const u8* __restrict__ bt,
    double* __restrict__ p3)
{
    __shared__ alignas(16) u8 lds[2][16384];
    const int b0 = blockIdx.x << 7;    // 64 row tiles
    const int j0 = blockIdx.y << 7;    // 32 col tiles
    const int t = threadIdx.x, l = t & 63, wv = t >> 6;
    const int wr = wv >> 1, wc = wv & 1;

    // DMA: thread t owns LDS slot (row4 = t>>2, pos = t&3); it must fetch
    // logical chunk pos ^ f(row4), f(r) = (r>>1)&3.  f(r+64) == f(r).
    const int row4 = t >> 2, pos = t & 3;
    const int chunk = pos ^ ((row4 >> 1) & 3);
    const u8* srcA = m8 + ((size_t)(b0 + row4) << 12) + ((size_t)chunk << 4);
    const u8* srcB = bt + ((size_t)(j0 + row4) << 12) + ((size_t)chunk << 4);

    // fragment read: row r = (w?<<6)+(fr<<4)+(l&15), logical chunk l>>4,
    // slot = (l>>4) ^ f(r); f(r) = ((l&15)>>1)&3 independent of fr/wave.
    const int slot = ((l >> 4) ^ ((l >> 1) & 3)) & 3;
    const int frbase = ((wr << 6) + (l & 15)) * 64 + (slot << 4);
    const int fcbase = 8192 + ((wc << 6) + (l & 15)) * 64 + (slot << 4);

    i32x4 acc[4][4];
    #pragma unroll
    for (int i = 0; i < 4; ++i)
        #pragma unroll
        for (int j = 0; j < 4; ++j) acc[i][j] = (i32x4){0, 0, 0, 0};

    auto stage = [&](int s, int buf) {
        const u8* sA = srcA + (s << 6);
        const u8* sB = srcB + (s << 6);
        u8* dA = &lds[buf][(size_t)wv << 10];          // wave-uniform bases
        u8* dB = &lds[buf][8192 + ((size_t)wv << 10)];
        gload_lds16(sA, dA);
        gload_lds16(sA + ((size_t)64 << 12), dA + 4096);
        gload_lds16(sB, dB);
        gload_lds16(sB + ((size_t)64 << 12), dB + 4096);
    };

    stage(0, 0);
    __syncthreads();   // buffer 0 ready

    #pragma unroll 1
    for (int ks = 0; ks < 64; ++ks) {
        const int cb = ks & 1;
        if (ks < 63) stage(ks + 1, cb ^ 1);   // async, lands during compute
        const u8* L = lds[cb];
        i32x4 a[4], b[4];
        #pragma unroll
        for (int f = 0; f < 4; ++f) {
            a[f] = *(const i32x4*)&L[frbase + f * 1024];
            b[f] = *(const i32x4*)&L[fcbase + f * 1024];
        }
        #pragma unroll
        for (int fr = 0; fr < 4; ++fr)
            #pragma unroll
            for (int fc = 0; fc < 4; ++fc)
                acc[fr][fc] = __builtin_amdgcn_mfma_i32_16x16x64_i8(
                    a[fr], b[fc], acc[fr][fc], 0, 0, 0);
        __syncthreads();   // reads of cb done + (cb^1) DMA drained
    }

    // epilogue: C/D map col=l&15, row=(l>>4)*4+q (m89/m121, dtype-independent)
    float part = 0.0f;
    const int col = j0 + (wc << 6) + (l & 15);
    #pragma unroll
    for (int fr = 0; fr < 4; ++fr)
        #pragma unroll
        for (int q = 0; q < 4; ++q) {
            size_t rbase = ((size_t)(b0 + (wr << 6) + (fr << 4) + ((l >> 4) << 2) + q) << 12) + col;
            #pragma unroll
            for (int fc = 0; fc < 4; ++fc) {
                float yv = y[rbase + (fc << 4)];
                float hv = yhat[rbase + (fc << 4)];
                float e = yv - hv;
                float wgt = 0.1f * (float)acc[fr][fc][q] + (yv != 0.0f ? 1.0f : 0.0f);
                part = fmaf(e * e, wgt, part);
            }
        }

    for (int off = 32; off; off >>= 1) part += __shfl_down(part, off, 64);
    float* red = (float*)lds;
    __syncthreads();
    if ((t & 63) == 0) red[t >> 6] = part;
    __syncthreads();
    if (t == 0)
        p3[(size_t)blockIdx.y * gridDim.x + blockIdx.x] =
            (double)red[0] + (double)red[1] + (double)red[2] + (double)red[3];
}

// ================= popcount fallback path (R8, passing @288us) =================

__global__ __launch_bounds__(256) void k1_pack_mask(
    const float* __restrict__ y, u64* __restrict__ mbT, u64* __restrict__ pcnt)
{
    __shared__ unsigned rc[4];
    const unsigned t = threadIdx.x;
    const unsigned lane = t & 63;
    const float4* y4 = (const float4*)y;
    u64 qi = (u64)blockIdx.x * 256 + t;
    const u64 stride = (u64)2048 * 256;
    unsigned lcnt = 0;
    #pragma unroll 4
    for (int it = 0; it < 16; ++it, qi += stride) {
        float4 v = y4[qi];
        u64 b0 = __ballot(v.x != 0.0f);
        u64 b1 = __ballot(v.y != 0.0f);
        u64 b2 = __ballot(v.z != 0.0f);
        u64 b3 = __ballot(v.w != 0.0f);
        lcnt += (v.x != 0.0f) + (v.y != 0.0f) + (v.z != 0.0f) + (v.w != 0.0f);
        if (lane < 4) {
            unsigned sh = lane << 4;
            u64 word = ((b0 >> sh) & 0xFFFFull)
                     | (((b1 >> sh) & 0xFFFFull) << 16)
                     | (((b2 >> sh) & 0xFFFFull) << 32)
                     | (((b3 >> sh) & 0xFFFFull) << 48);
            u64 gw = ((qi - lane) >> 4) + lane;
            mbT[((gw & 63) << 13) + (gw >> 6)] = word;
        }
    }
    for (int off = 32; off; off >>= 1) lcnt += __shfl_down(lcnt, off, 64);
    if ((t & 63) == 0) rc[t >> 6] = lcnt;
    __syncthreads();
    if (t == 0) pcnt[blockIdx.x] = (u64)rc[0] + rc[1] + rc[2] + rc[3];
}

__global__ __launch_bounds__(256) void k2_pack_w(
    const float* __restrict__ W, u64* __restrict__ wbT)
{
    __shared__ float tile[64][65];
    const int j0 = blockIdx.x * 64;
    const int w  = blockIdx.y;
    const int i0 = w * 64;
    const int t = threadIdx.x;
    #pragma unroll
    for (int k = 0; k < 16; ++k) {
        int lin = t + (k << 8);
        int r = lin >> 6, c = lin & 63;
        tile[r][c] = W[(size_t)(i0 + r) * NS + (j0 + c)];
    }
    __syncthreads();
    const int lane = t & 63;
    const int wvv = t >> 6;
    const int pr = ((lane & 15) << 2) + (lane >> 4);
    for (int jj = wvv; jj < 64; jj += 4) {
        u64 bal = __ballot(tile[pr][jj] != 0.0f);
        if (lane == 0) wbT[((size_t)w << 12) + (j0 + jj)] = bal;
    }
}

__global__ __launch_bounds__(256) void k3_main(
    const float* __restrict__ y, const float* __restrict__ yhat,
    const u64* __restrict__ mbT, const u64* __restrict__ wbT,
    double* __restrict__ p3)
{
    __shared__ alignas(16) u64 mT[16 * 128];
    __shared__ alignas(16) u64 wT[16 * 128];
    const int b0 = blockIdx.x << 7;
    const int j0 = blockIdx.y << 7;
    const int t  = threadIdx.x;
    const int r0 = (t >> 4) << 3;
    const int cj = t & 15;
    const unsigned sx = ((unsigned)cj >> 2) << 4;

    unsigned cnt[8][8];
    #pragma unroll
    for (int a = 0; a < 8; ++a)
        #pragma unroll
        for (int b = 0; b < 8; ++b) cnt[a][b] = 0;

    char* mB = (char*)mT;
    char* wB = (char*)wT;

    #pragma unroll 1
    for (int s = 0; s < 4; ++s) {
        u64x2 gm[4], gq[4];
        #pragma unroll
        for (int k = 0; k < 4; ++k) {
            int lin = t + (k << 8);
            int wl = (s << 4) + (lin >> 6), c2 = lin & 63;
            gm[k] = *(const u64x2*)&mbT[((size_t)wl << 13) + b0 + 2 * c2];
            gq[k] = *(const u64x2*)&wbT[((size_t)wl << 12) + j0 + 2 * c2];
        }
        __syncthreads();
        #pragma unroll
        for (int k = 0; k < 4; ++k) {
            int lin = t + (k << 8);
            int wl = lin >> 6, c2 = lin & 63;
            int p = c2 ^ ((c2 >> 4) & 3);
            *(u64x2*)(mB + (wl << 10) + (c2 << 4)) = gm[k];
            *(u64x2*)(wB + (wl << 10) + (p << 4)) = gq[k];
        }
        __syncthreads();

        unsigned mo = (unsigned)(r0 << 3);
        unsigned qs = (unsigned)(cj << 6) + sx;
        #pragma unroll 2
        for (int w = 0; w < 16; ++w) {
            unsigned ml[16], ql[16];
            #pragma unroll
            for (int k = 0; k < 4; ++k) {
                uint4 a = *(const uint4*)(mB + mo + (k << 4));
                ml[4 * k + 0] = a.x; ml[4 * k + 1] = a.y;
                ml[4 * k + 2] = a.z; ml[4 * k + 3] = a.w;
                uint4 b = *(const uint4*)(wB + (qs ^ (unsigned)(k << 4)));
                ql[4 * k + 0] = b.x; ql[4 * k + 1] = b.y;
                ql[4 * k + 2] = b.z; ql[4 * k + 3] = b.w;
            }
            #pragma unroll
            for (int aa = 0; aa < 8; ++aa)
                #pragma unroll
                for (int bb = 0; bb < 8; ++bb) {
                    unsigned x0 = ml[2 * aa] & ql[2 * bb];
                    unsigned x1 = ml[2 * aa + 1] & ql[2 * bb + 1];
                    asm("v_bcnt_u32_b32 %0, %1, %0" : "+v"(cnt[aa][bb]) : "v"(x0));
                    asm("v_bcnt_u32_b32 %0, %1, %0" : "+v"(cnt[aa][bb]) : "v"(x1));
                }
            mo += 1024; qs += 1024;
        }
    }

    float part = 0.0f;
    const int c0 = cj << 3;
    #pragma unroll
    for (int aa = 0; aa < 8; ++aa) {
        size_t off = ((size_t)(b0 + r0 + aa) << 12) + (size_t)(j0 + c0);
        float ys[8], hs[8];
        *(float4*)&ys[0] = *(const float4*)(y + off);
        *(float4*)&ys[4] = *(const float4*)(y + off + 4);
        *(float4*)&hs[0] = *(const float4*)(yhat + off);
        *(float4*)&hs[4] = *(const float4*)(yhat + off + 4);
        #pragma unroll
        for (int bb = 0; bb < 8; ++bb) {
            float e = ys[bb] - hs[bb];
            float wgt = 0.1f * (float)cnt[aa][bb] + (ys[bb] != 0.0f ? 1.0f : 0.0f);
            part = fmaf(e * e, wgt, part);
        }
    }

    for (int off = 32; off; off >>= 1) part += __shfl_down(part, off, 64);
    float* red = (float*)mT;
    __syncthreads();
    if ((t & 63) == 0) red[t >> 6] = part;
    __syncthreads();
    if (t == 0)
        p3[(size_t)blockIdx.y * gridDim.x + blockIdx.x] =
            (double)red[0] + (double)red[1] + (double)red[2] + (double)red[3];
}

// ---------------- K4: final reduce + sqrt (shared) ----------------
__global__ __launch_bounds__(256) void k4_final(
    const u64* __restrict__ pcnt, const double* __restrict__ p3, float* __restrict__ out)
{
    __shared__ double rs[4];
    __shared__ u64 rcc[4];
    double s3 = 0.0;
    u64 c = 0;
    for (int i = threadIdx.x; i < 2048; i += 256) { s3 += p3[i]; c += pcnt[i]; }
    for (int off = 32; off; off >>= 1) {
        s3 += __shfl_down(s3, off, 64);
        c  += __shfl_down(c, off, 64);
    }
    int wv = threadIdx.x >> 6;
    if ((threadIdx.x & 63) == 0) { rs[wv] = s3; rcc[wv] = c; }
    __syncthreads();
    if (threadIdx.x == 0) {
        double S3 = rs[0] + rs[1] + rs[2] + rs[3];
        double C  = (double)(rcc[0] + rcc[1] + rcc[2] + rcc[3]);
        out[0] = (float)sqrt(S3 / C + 1e-6);
    }
}

extern "C" void kernel_launch(void* const* d_in, const int* in_sizes, int n_in,
                              void* d_out, int out_size, void* d_ws, size_t ws_size,
                              hipStream_t stream) {
    const float* yhat = (const float*)d_in[0];
    const float* y    = (const float*)d_in[1];
    const float* W    = (const float*)d_in[2];
    char* ws = (char*)d_ws;
    u64*    pcnt = (u64*)(ws + OFF_CNT);
    double* p3   = (double*)(ws + OFF_P3);

    if (ws_size >= WS_NEED) {
        u32* m8 = (u32*)(ws + OFF_M8);
        u32* bt = (u32*)(ws + OFF_BT);
        k1b_mask8<<<dim3(2048), dim3(256), 0, stream>>>(y, m8, pcnt);
        k2b_bt<<<dim3(64, 64), dim3(256), 0, stream>>>(W, bt);
        k3b_mfma<<<dim3(64, 32), dim3(256), 0, stream>>>(
            y, yhat, (const u8*)m8, (const u8*)bt, p3);
        k4_final<<<dim3(1), dim3(256), 0, stream>>>(pcnt, p3, (float*)d_out);
    } else {
        u64* mbT = (u64*)(ws + OFF_MB);
        u64* wbT = (u64*)(ws + OFF_WB);
        k1_pack_mask<<<dim3(2048), dim3(256), 0, stream>>>(y, mbT, pcnt);
        k2_pack_w<<<dim3(64, 64), dim3(256), 0, stream>>>(W, wbT);
        k3_main<<<dim3(64, 32), dim3(256), 0, stream>>>(y, yhat, mbT, wbT, p3);
        k4_final<<<dim3(1), dim3(256), 0, stream>>>(pcnt, p3, (float*)d_out);
    }
}